// Round 29
// baseline (154.248 us; speedup 1.0000x reference)
//
#include <hip/hip_runtime.h>
#include <hip/hip_bf16.h>
#include <math.h>

#define CC  128
#define RLD 136            // halves stride for [64][128] bf16 LDS tiles (272B)
#define VLD 72             // halves stride for vT buffer (144B)

typedef __attribute__((ext_vector_type(8))) short bf16x8;
typedef __attribute__((ext_vector_type(4))) float f32x4;

#define MFMA16(a, b, c) __builtin_amdgcn_mfma_f32_16x16x32_bf16((a), (b), (c), 0, 0, 0)

__device__ __forceinline__ unsigned short f2bf(float f) {
    unsigned int u = __float_as_uint(f);
    u += 0x7FFFu + ((u >> 16) & 1u);
    return (unsigned short)(u >> 16);
}
__device__ __forceinline__ float bf2f(unsigned short h) {
    return __uint_as_float(((unsigned int)h) << 16);
}
__device__ __forceinline__ unsigned int f2bf2u(float lo, float hi) {
    __hip_bfloat162 h = __float22bfloat162_rn(make_float2(lo, hi));
    union { __hip_bfloat162 h2; unsigned int u; } cv; cv.h2 = h;
    return cv.u;
}
__device__ __forceinline__ bf16x8 mk_bf16x8(unsigned int a0, unsigned int a1,
                                            unsigned int a2, unsigned int a3) {
    union { uint4 u; bf16x8 b; } cv;
    cv.u = make_uint4(a0, a1, a2, a3);
    return cv.b;
}
// tanh-approx gelu via exp2 (branch-free)
__device__ __forceinline__ float gelu_tanh(float v) {
    float t = v * fmaf(0.102951871f, v * v, 2.302110084f);
    float s = __builtin_amdgcn_exp2f(t);
    return v - v * __builtin_amdgcn_rcpf(1.0f + s);
}

// packed-weight half offsets in d_ws
#define OQ  0
#define OKk 16384
#define OV  32768
#define OP  49152
#define O1  65536
#define O2  131072

// ---- FUSED weight pre-pack: all 6 weights in ONE launch (saves 5 graph nodes).
__global__ void pack_all(const float* __restrict__ wq, const float* __restrict__ wk,
                         const float* __restrict__ wv, const float* __restrict__ wp,
                         const float* __restrict__ w1, const float* __restrict__ w2,
                         unsigned short* __restrict__ ws16) {
    int b = blockIdx.x;
    const float* src; unsigned short* dst; int K, N, mode, lb; float scale;
    if (b < 64)       { src = wq; dst = ws16 + OQ;  K = 128; N = 128; mode = 1; scale = 0.3606737602f; lb = b; }
    else if (b < 128) { src = wk; dst = ws16 + OKk; K = 128; N = 128; mode = 1; scale = 1.0f; lb = b - 64; }
    else if (b < 192) { src = wv; dst = ws16 + OV;  K = 128; N = 128; mode = 1; scale = 1.0f; lb = b - 128; }
    else if (b < 256) { src = wp; dst = ws16 + OP;  K = 128; N = 128; mode = 0; scale = 1.0f; lb = b - 192; }
    else if (b < 512) { src = w1; dst = ws16 + O1;  K = 128; N = 512; mode = 0; scale = 1.0f; lb = b - 256; }
    else              { src = w2; dst = ws16 + O2;  K = 512; N = 128; mode = 2; scale = 1.0f; lb = b - 512; }
    int i   = lb * 256 + (int)threadIdx.x;      // sizes are exact multiples of 256
    int j   = i & 7;
    int l   = (i >> 3) & 63;
    int tkt = i >> 9;
    int KT  = K >> 5;
    int nt  = tkt / KT;
    int kt  = tkt - nt * KT;
    int lg  = l >> 4;
    int k;
    if (mode == 2) {
        int kp = (j < 4) ? (lg * 4 + j) : (16 + lg * 4 + (j - 4));
        k = kt * 32 + kp;
    } else {
        k = kt * 32 + lg * 8 + j;
    }
    int n = nt * 16 + (l & 15);
    float v = (mode == 1) ? src[(n >> 4) * (K * 16) + k * 16 + (n & 15)]
                          : src[k * N + n];
    dst[i] = f2bf(v * scale);
}

// One block = 1 batch element (64 rows). 512 threads = 8 waves. ~70 KB LDS -> 2 blocks/CU.
__global__ __launch_bounds__(512, 4) void block_fused(
    const float* __restrict__ x,
    const unsigned short* __restrict__ wpk,
    const float* __restrict__ bp,
    const float* __restrict__ b1, const float* __restrict__ b2,
    const float* __restrict__ g1, const float* __restrict__ be1,
    const float* __restrict__ g2, const float* __restrict__ be2,
    float* __restrict__ out)
{
    __shared__ __align__(16) unsigned short A [9216];  // h -> h2 (stays live through FF)
    __shared__ __align__(16) unsigned short Bq[8704];  // q -> attn concat -> FF exch (rt 0,1)
    __shared__ __align__(16) unsigned short Ck[8704];  // k -> x2
    __shared__ __align__(16) unsigned short Vv[9216];  // vT(permuted) -> FF exch (rt 2,3)

    const int tid  = threadIdx.x;
    const int lane = tid & 63;
    const int wave = tid >> 6;
    const int l15  = lane & 15;
    const int lg   = lane >> 4;
    const int rt   = wave >> 1;         // GEMM-phase row tile (proj/FF)
    const int cg   = wave & 1;          // GEMM-phase column group / FF k-half
    const int row0 = rt * 16 + lg * 4;
    const int hcol = wave * 16;         // this wave's head columns

    const float* xb = x   + (size_t)blockIdx.x * (64 * CC);
    float*       ob = out + (size_t)blockIdx.x * (64 * CC);

    // early-issue QKV weight loads (no deps): latency hides under LN1 (r21 pattern).
    bf16x8 wq4[4], wk4[4], wv4[4];
    {
        const unsigned short* wqb = wpk + OQ  + wave * 2048;
        const unsigned short* wkb = wpk + OKk + wave * 2048;
        const unsigned short* wvb = wpk + OV  + wave * 2048;
        #pragma unroll
        for (int kt = 0; kt < 4; ++kt) {
            wq4[kt] = *(const bf16x8*)&wqb[(kt * 64 + lane) * 8];
            wk4[kt] = *(const bf16x8*)&wkb[(kt * 64 + lane) * 8];
            wv4[kt] = *(const bf16x8*)&wvb[(kt * 64 + lane) * 8];
        }
    }

    // ---------------- LN1: x -> A (h, bf16); WIDE-LANE one-pass ----------------
    // 16-lane row groups: lane owns 8 cols, 4 rows/iter, 4-step butterfly.
    {
        float gg[8], bb[8];
        #pragma unroll
        for (int j = 0; j < 8; ++j) {
            gg[j] = g1[l15 * 8 + j];
            bb[j] = be1[l15 * 8 + j];
        }
        const int grp = lane >> 4;
        #pragma unroll
        for (int it = 0; it < 2; ++it) {
            int r = wave * 8 + it * 4 + grp;
            float4 xa = *(const float4*)&xb[r * CC + l15 * 8];
            float4 xc = *(const float4*)&xb[r * CC + l15 * 8 + 4];
            float xv[8] = {xa.x, xa.y, xa.z, xa.w, xc.x, xc.y, xc.z, xc.w};
            float s = 0.f, q = 0.f;
            #pragma unroll
            for (int j = 0; j < 8; ++j) { s += xv[j]; q = fmaf(xv[j], xv[j], q); }
            #pragma unroll
            for (int off = 1; off < 16; off <<= 1) {
                s += __shfl_xor(s, off);
                q += __shfl_xor(q, off);
            }
            float mean = s * (1.0f / CC);
            float var  = fmaf(-mean, mean, q * (1.0f / CC));
            float rstd = __builtin_amdgcn_rsqf(var + 1e-5f);
            unsigned int u0 = f2bf2u(fmaf(gg[0], (xv[0] - mean) * rstd, bb[0]),
                                     fmaf(gg[1], (xv[1] - mean) * rstd, bb[1]));
            unsigned int u1 = f2bf2u(fmaf(gg[2], (xv[2] - mean) * rstd, bb[2]),
                                     fmaf(gg[3], (xv[3] - mean) * rstd, bb[3]));
            unsigned int u2 = f2bf2u(fmaf(gg[4], (xv[4] - mean) * rstd, bb[4]),
                                     fmaf(gg[5], (xv[5] - mean) * rstd, bb[5]));
            unsigned int u3 = f2bf2u(fmaf(gg[6], (xv[6] - mean) * rstd, bb[6]),
                                     fmaf(gg[7], (xv[7] - mean) * rstd, bb[7]));
            *(uint4*)&A[r * RLD + l15 * 8] = make_uint4(u0, u1, u2, u3);
        }
    }
    __syncthreads();

    // ---------------- QKV, head-major: wave = head; weights preloaded ----
    {
        #pragma unroll
        for (int rt2 = 0; rt2 < 4; ++rt2) {
            bf16x8 la[4];
            #pragma unroll
            for (int kt = 0; kt < 4; ++kt)
                la[kt] = *(const bf16x8*)&A[(rt2 * 16 + l15) * RLD + kt * 32 + lg * 8];
            f32x4 cq = {0.f,0.f,0.f,0.f}, ck = {0.f,0.f,0.f,0.f}, cv = {0.f,0.f,0.f,0.f};
            __builtin_amdgcn_s_setprio(1);
            #pragma unroll
            for (int kt = 0; kt < 4; ++kt) {
                cq = MFMA16(la[kt], wq4[kt], cq);
                ck = MFMA16(la[kt], wk4[kt], ck);
                cv = MFMA16(la[kt], wv4[kt], cv);
            }
            __builtin_amdgcn_s_setprio(0);
            int rw = rt2 * 16 + lg * 4;
            unsigned int q01 = f2bf2u(cq[0], cq[1]), q23 = f2bf2u(cq[2], cq[3]);
            unsigned int k01 = f2bf2u(ck[0], ck[1]), k23 = f2bf2u(ck[2], ck[3]);
            unsigned int v01 = f2bf2u(cv[0], cv[1]), v23 = f2bf2u(cv[2], cv[3]);
            int o = rw * RLD + hcol + l15;
            Bq[o]           = (unsigned short)q01;
            Bq[o + RLD]     = (unsigned short)(q01 >> 16);
            Bq[o + 2 * RLD] = (unsigned short)q23;
            Bq[o + 3 * RLD] = (unsigned short)(q23 >> 16);
            Ck[o]           = (unsigned short)k01;
            Ck[o + RLD]     = (unsigned short)(k01 >> 16);
            Ck[o + 2 * RLD] = (unsigned short)k23;
            Ck[o + 3 * RLD] = (unsigned short)(k23 >> 16);
            int vslot = (rt2 >> 1) * 32 + lg * 8 + (rt2 & 1) * 4;
            *(uint2*)&Vv[(hcol + l15) * VLD + vslot] = make_uint2(v01, v23);
        }
    }

    // prefetch proj's residual x (hides under attention); static indices
    float xpre[16];
    #pragma unroll
    for (int ntl = 0; ntl < 4; ++ntl) {
        int col = (cg * 4 + ntl) * 16 + l15;
        #pragma unroll
        for (int r = 0; r < 4; ++r)
            xpre[ntl * 4 + r] = xb[(row0 + r) * CC + col];
    }
    // NO barrier: attention reads only this wave's own q/k/vT

    // ---------------- attention: wave = head, swapped scores, in-register P ----------------
    bf16x8 pp[4];
    {
        int nt0 = cg * 4;
        #pragma unroll
        for (int kt = 0; kt < 4; ++kt)
            pp[kt] = *(const bf16x8*)&wpk[OP + ((nt0 * 4 + kt) * 64 + lane) * 8];
    }
    {
        bf16x8 zf = {0, 0, 0, 0, 0, 0, 0, 0};
        bf16x8 kf[4];
        #pragma unroll
        for (int st = 0; st < 4; ++st)
            kf[st] = (lane < 32) ? *(const bf16x8*)&Ck[(st * 16 + l15) * RLD + hcol + lg * 8] : zf;
        bf16x8 bvf[2];
        #pragma unroll
        for (int kt = 0; kt < 2; ++kt)
            bvf[kt] = *(const bf16x8*)&Vv[(hcol + l15) * VLD + kt * 32 + lg * 8];

        f32x4 ocs[4];
        #pragma unroll
        for (int mt = 0; mt < 4; ++mt) {
            bf16x8 qf = zf;
            if (lane < 32)
                qf = *(const bf16x8*)&Bq[(mt * 16 + l15) * RLD + hcol + lg * 8];
            f32x4 sfr[4];
            __builtin_amdgcn_s_setprio(1);
            #pragma unroll
            for (int st = 0; st < 4; ++st) {
                sfr[st] = (f32x4){0.f, 0.f, 0.f, 0.f};
                if (st <= mt) sfr[st] = MFMA16(kf[st], qf, sfr[st]);
            }
            __builtin_amdgcn_s_setprio(0);
            float e[4][4];
            float sum = 0.f;
            #pragma unroll
            for (int st = 0; st < 4; ++st) {
                #pragma unroll
                for (int r = 0; r < 4; ++r) {
                    float ev = 0.f;
                    if (st < mt) ev = __builtin_amdgcn_exp2f(sfr[st][r]);
                    else if (st == mt)
                        ev = (lg * 4 + r <= l15) ? __builtin_amdgcn_exp2f(sfr[st][r]) : 0.f;
                    e[st][r] = ev;
                    sum += ev;
                }
            }
            sum += __shfl_xor(sum, 16);
            sum += __shfl_xor(sum, 32);
            float inv = __builtin_amdgcn_rcpf(sum);
            unsigned int u[4][2];
            #pragma unroll
            for (int st = 0; st < 4; ++st) {
                if (st <= mt) {
                    u[st][0] = f2bf2u(e[st][0] * inv, e[st][1] * inv);
                    u[st][1] = f2bf2u(e[st][2] * inv, e[st][3] * inv);
                } else { u[st][0] = 0u; u[st][1] = 0u; }
            }
            f32x4 oc = {0.f, 0.f, 0.f, 0.f};
            __builtin_amdgcn_s_setprio(1);
            #pragma unroll
            for (int kt = 0; kt < 2; ++kt) {
                if (kt <= (mt >> 1)) {
                    bf16x8 pa = mk_bf16x8(u[2 * kt][0], u[2 * kt][1],
                                          u[2 * kt + 1][0], u[2 * kt + 1][1]);
                    oc = MFMA16(pa, bvf[kt], oc);
                }
            }
            __builtin_amdgcn_s_setprio(0);
            ocs[mt] = oc;
        }
        #pragma unroll
        for (int mt = 0; mt < 4; ++mt) {
            unsigned int u01 = f2bf2u(ocs[mt][0], ocs[mt][1]);
            unsigned int u23 = f2bf2u(ocs[mt][2], ocs[mt][3]);
            int o = (mt * 16 + lg * 4) * RLD + hcol + l15;
            Bq[o]           = (unsigned short)u01;
            Bq[o + RLD]     = (unsigned short)(u01 >> 16);
            Bq[o + 2 * RLD] = (unsigned short)u23;
            Bq[o + 3 * RLD] = (unsigned short)(u23 >> 16);
        }
    }
    __syncthreads();   // proj reads all columns of Bq

    // ---------------- proj + residual: x2 = x + attn @ Wp + bp -> Ck + x2r regs ----
    // x2 stays in registers (x2r) for the epilogue: the epilogue's cols/rows are
    // EXACTLY this wave's proj fragment (cg half matches). xpre dies here ->
    // x2r takes its register slots (net-zero live-range change; NOT the r14 trap).
    float x2r[16];
    {
        bf16x8 pa[4];
        #pragma unroll
        for (int kt = 0; kt < 4; ++kt)
            pa[kt] = *(const bf16x8*)&Bq[(rt * 16 + l15) * RLD + kt * 32 + lg * 8];
        {
            int nt = cg * 4;
            f32x4 c = {0.f, 0.f, 0.f, 0.f};
            #pragma unroll
            for (int kt = 0; kt < 4; ++kt)
                c = MFMA16(pa[kt], pp[kt], c);
            int col = nt * 16 + l15;
            float bpv = bp[col];
            #pragma unroll
            for (int r = 0; r < 4; ++r) x2r[r] = xpre[r] + c[r] + bpv;
            unsigned int u01 = f2bf2u(x2r[0], x2r[1]);
            unsigned int u23 = f2bf2u(x2r[2], x2r[3]);
            int o = row0 * RLD + col;
            Ck[o]           = (unsigned short)u01;
            Ck[o + RLD]     = (unsigned short)(u01 >> 16);
            Ck[o + 2 * RLD] = (unsigned short)u23;
            Ck[o + 3 * RLD] = (unsigned short)(u23 >> 16);
        }
        #pragma unroll
        for (int ntl = 1; ntl < 4; ++ntl) {
            int nt = cg * 4 + ntl;
            f32x4 c = {0.f, 0.f, 0.f, 0.f};
            #pragma unroll
            for (int kt = 0; kt < 4; ++kt) {
                bf16x8 b = *(const bf16x8*)&wpk[OP + ((nt * 4 + kt) * 64 + lane) * 8];
                c = MFMA16(pa[kt], b, c);
            }
            int col = nt * 16 + l15;
            float bpv = bp[col];
            #pragma unroll
            for (int r = 0; r < 4; ++r) x2r[ntl * 4 + r] = xpre[ntl * 4 + r] + c[r] + bpv;
            unsigned int u01 = f2bf2u(x2r[ntl * 4 + 0], x2r[ntl * 4 + 1]);
            unsigned int u23 = f2bf2u(x2r[ntl * 4 + 2], x2r[ntl * 4 + 3]);
            int o = row0 * RLD + col;
            Ck[o]           = (unsigned short)u01;
            Ck[o + RLD]     = (unsigned short)(u01 >> 16);
            Ck[o + 2 * RLD] = (unsigned short)u23;
            Ck[o + 3 * RLD] = (unsigned short)(u23 >> 16);
        }
    }
    __syncthreads();   // LN2 reads all cols of Ck; also: last Bq reads complete

    // early-issue FF c=0 weight loads (no LDS dependency): latency hides under LN2.
    bf16x8 pw0[4], pw1[4], pb2[8];
    {
        int t0 = cg * 16;
        #pragma unroll
        for (int kt = 0; kt < 4; ++kt) {
            pw0[kt] = *(const bf16x8*)&wpk[O1 + ((t0 * 4 + kt) * 64 + lane) * 8];
            pw1[kt] = *(const bf16x8*)&wpk[O1 + (((t0 + 1) * 4 + kt) * 64 + lane) * 8];
        }
        int kc = cg * 8;
        #pragma unroll
        for (int nt = 0; nt < 8; ++nt)
            pb2[nt] = *(const bf16x8*)&wpk[O2 + ((nt * 16 + kc) * 64 + lane) * 8];
    }

    // ---------------- LN2: Ck(x2) -> A(h2); WIDE-LANE one-pass ----------------
    {
        float gg[8], bb[8];
        #pragma unroll
        for (int j = 0; j < 8; ++j) {
            gg[j] = g2[l15 * 8 + j];
            bb[j] = be2[l15 * 8 + j];
        }
        const int grp = lane >> 4;
        #pragma unroll
        for (int it = 0; it < 2; ++it) {
            int r = wave * 8 + it * 4 + grp;
            bf16x8 cv = *(const bf16x8*)&Ck[r * RLD + l15 * 8];
            float xv[8];
            #pragma unroll
            for (int j = 0; j < 8; ++j) xv[j] = bf2f((unsigned short)cv[j]);
            float s = 0.f, q = 0.f;
            #pragma unroll
            for (int j = 0; j < 8; ++j) { s += xv[j]; q = fmaf(xv[j], xv[j], q); }
            #pragma unroll
            for (int off = 1; off < 16; off <<= 1) {
                s += __shfl_xor(s, off);
                q += __shfl_xor(q, off);
            }
            float mean = s * (1.0f / CC);
            float var  = fmaf(-mean, mean, q * (1.0f / CC));
            float rstd = __builtin_amdgcn_rsqf(var + 1e-5f);
            unsigned int u0 = f2bf2u(fmaf(gg[0], (xv[0] - mean) * rstd, bb[0]),
                                     fmaf(gg[1], (xv[1] - mean) * rstd, bb[1]));
            unsigned int u1 = f2bf2u(fmaf(gg[2], (xv[2] - mean) * rstd, bb[2]),
                                     fmaf(gg[3], (xv[3] - mean) * rstd, bb[3]));
            unsigned int u2 = f2bf2u(fmaf(gg[4], (xv[4] - mean) * rstd, bb[4]),
                                     fmaf(gg[5], (xv[5] - mean) * rstd, bb[5]));
            unsigned int u3 = f2bf2u(fmaf(gg[6], (xv[6] - mean) * rstd, bb[6]),
                                     fmaf(gg[7], (xv[7] - mean) * rstd, bb[7]));
            *(uint4*)&A[r * RLD + l15 * 8] = make_uint4(u0, u1, u2, u3);
        }
    }
    __syncthreads();

    // ---------------- FF, wave-private K-split (no LDS f1, no inner barriers) -------
    {
        bf16x8 ha[4];
        #pragma unroll
        for (int kt = 0; kt < 4; ++kt)
            ha[kt] = *(const bf16x8*)&A[(rt * 16 + l15) * RLD + kt * 32 + lg * 8];
        f32x4 facc[8];
        #pragma unroll
        for (int n = 0; n < 8; ++n) facc[n] = (f32x4){0.f, 0.f, 0.f, 0.f};

        // peeled c=0 using the prefetched FF1 + FF2 weights
        {
            int t0 = cg * 16;
            f32x4 c0 = {0.f,0.f,0.f,0.f}, c1 = {0.f,0.f,0.f,0.f};
            #pragma unroll
            for (int kt = 0; kt < 4; ++kt) {
                c0 = MFMA16(pw0[kt], ha[kt], c0);   // transposed: C[col=token][row=f]
                c1 = MFMA16(pw1[kt], ha[kt], c1);
            }
            int fb = t0 * 16 + lg * 4;
            float g0[4], g1v[4];
            #pragma unroll
            for (int r = 0; r < 4; ++r) g0[r]  = gelu_tanh(c0[r] + b1[fb + r]);
            #pragma unroll
            for (int r = 0; r < 4; ++r) g1v[r] = gelu_tanh(c1[r] + b1[fb + 16 + r]);
            bf16x8 pa = mk_bf16x8(f2bf2u(g0[0],  g0[1]),  f2bf2u(g0[2],  g0[3]),
                                  f2bf2u(g1v[0], g1v[1]), f2bf2u(g1v[2], g1v[3]));
            #pragma unroll
            for (int nt = 0; nt < 8; ++nt)
                facc[nt] = MFMA16(pa, pb2[nt], facc[nt]);
        }

        #pragma unroll 1
        for (int c = 1; c < 8; ++c) {            // K32 chunk = 2 f-tiles
            int t0 = cg * 16 + 2 * c;
            f32x4 c0 = {0.f,0.f,0.f,0.f}, c1 = {0.f,0.f,0.f,0.f};
            #pragma unroll
            for (int kt = 0; kt < 4; ++kt) {
                bf16x8 w0  = *(const bf16x8*)&wpk[O1 + ((t0 * 4 + kt) * 64 + lane) * 8];
                bf16x8 w1f = *(const bf16x8*)&wpk[O1 + (((t0 + 1) * 4 + kt) * 64 + lane) * 8];
                c0 = MFMA16(w0,  ha[kt], c0);    // transposed: C[col=token][row=f]
                c1 = MFMA16(w1f, ha[kt], c1);
            }
            int fb = t0 * 16 + lg * 4;
            float g0[4], g1v[4];
            #pragma unroll
            for (int r = 0; r < 4; ++r) g0[r]  = gelu_tanh(c0[r] + b1[fb + r]);
            #pragma unroll
            for (int r = 0; r < 4; ++r) g1v[r] = gelu_tanh(c1[r] + b1[fb + 16 + r]);
            bf16x8 pa = mk_bf16x8(f2bf2u(g0[0],  g0[1]),  f2bf2u(g0[2],  g0[3]),
                                  f2bf2u(g1v[0], g1v[1]), f2bf2u(g1v[2], g1v[3]));
            int kc = cg * 8 + c;
            #pragma unroll
            for (int nt = 0; nt < 8; ++nt) {
                bf16x8 b = *(const bf16x8*)&wpk[O2 + ((nt * 16 + kc) * 64 + lane) * 8];
                facc[nt] = MFMA16(pa, b, facc[nt]);
            }
        }

        // NO barrier here: exchange targets Bq (dead since proj) and Vv (dead
        // since attention) — A(h2) is never overwritten (r27 layout).
        float* fb0 = (rt < 2) ? (float*)Bq : (float*)Vv;
        const int fbase = (rt & 1) * 2112;        // [16 tokens][132 f32] per tile
        if (cg == 0) {
            #pragma unroll
            for (int n2 = 0; n2 < 4; ++n2)
                #pragma unroll
                for (int r = 0; r < 4; ++r)
                    fb0[fbase + (lg * 4 + r) * 132 + (n2 + 4) * 16 + l15] = facc[n2 + 4][r];
        } else {
            #pragma unroll
            for (int n2 = 0; n2 < 4; ++n2)
                #pragma unroll
                for (int r = 0; r < 4; ++r)
                    fb0[fbase + (lg * 4 + r) * 132 + n2 * 16 + l15] = facc[n2][r];
        }
        __syncthreads();   // partner's partials visible
        // epilogue: out = x2(REGISTERS, f32 — more accurate than bf16 LDS) + ff + b2
        if (cg == 0) {
            #pragma unroll
            for (int n2 = 0; n2 < 4; ++n2) {
                int col = n2 * 16 + l15;
                float b2v = b2[col];
                #pragma unroll
                for (int r = 0; r < 4; ++r) {
                    int row = row0 + r;
                    ob[row * CC + col] = x2r[n2 * 4 + r] + facc[n2][r]
                                       + fb0[fbase + (lg * 4 + r) * 132 + col] + b2v;
                }
            }
        } else {
            #pragma unroll
            for (int n2 = 0; n2 < 4; ++n2) {
                int col = (n2 + 4) * 16 + l15;
                float b2v = b2[col];
                #pragma unroll
                for (int r = 0; r < 4; ++r) {
                    int row = row0 + r;
                    ob[row * CC + col] = x2r[n2 * 4 + r] + facc[n2 + 4][r]
                                       + fb0[fbase + (lg * 4 + r) * 132 + col] + b2v;
                }
            }
        }
    }
}

extern "C" void kernel_launch(void* const* d_in, const int* in_sizes, int n_in,
                              void* d_out, int out_size, void* d_ws, size_t ws_size,
                              hipStream_t stream) {
    (void)n_in; (void)out_size; (void)ws_size;
    const float* x   = (const float*)d_in[0];
    const float* wq  = (const float*)d_in[1];
    const float* wk  = (const float*)d_in[2];
    const float* wv  = (const float*)d_in[3];
    const float* wp  = (const float*)d_in[4];
    const float* bp  = (const float*)d_in[5];
    const float* w1  = (const float*)d_in[6];
    const float* b1  = (const float*)d_in[7];
    const float* w2  = (const float*)d_in[8];
    const float* b2  = (const float*)d_in[9];
    const float* g1  = (const float*)d_in[10];
    const float* be1 = (const float*)d_in[11];
    const float* g2  = (const float*)d_in[12];
    const float* be2 = (const float*)d_in[13];

    unsigned short* ws16 = (unsigned short*)d_ws;
    // all 6 weight packs in ONE launch (saves 5 graph-node overheads);
    // wq scale = HD^-0.5 * log2(e) folded inside (base-2 softmax domain)
    pack_all<<<768, 256, 0, stream>>>(wq, wk, wv, wp, w1, w2, ws16);

    int nblk = in_sizes[0] / (64 * CC);   // one block per batch element
    block_fused<<<dim3(nblk), dim3(512), 0, stream>>>(
        x, ws16, bp, b1, b2, g1, be1, g2, be2, (float*)d_out);
}

// Round 30
// 123.906 us; speedup vs baseline: 1.2449x; 1.2449x over previous
//
#include <hip/hip_runtime.h>
#include <hip/hip_bf16.h>
#include <math.h>

#define CC  128
#define RLD 136            // halves stride for [64][128] bf16 LDS tiles (272B)
#define VLD 72             // halves stride for vT buffer (144B)

typedef __attribute__((ext_vector_type(8))) short bf16x8;
typedef __attribute__((ext_vector_type(4))) float f32x4;

#define MFMA16(a, b, c) __builtin_amdgcn_mfma_f32_16x16x32_bf16((a), (b), (c), 0, 0, 0)

__device__ __forceinline__ unsigned short f2bf(float f) {
    unsigned int u = __float_as_uint(f);
    u += 0x7FFFu + ((u >> 16) & 1u);
    return (unsigned short)(u >> 16);
}
__device__ __forceinline__ float bf2f(unsigned short h) {
    return __uint_as_float(((unsigned int)h) << 16);
}
__device__ __forceinline__ unsigned int f2bf2u(float lo, float hi) {
    __hip_bfloat162 h = __float22bfloat162_rn(make_float2(lo, hi));
    union { __hip_bfloat162 h2; unsigned int u; } cv; cv.h2 = h;
    return cv.u;
}
__device__ __forceinline__ bf16x8 mk_bf16x8(unsigned int a0, unsigned int a1,
                                            unsigned int a2, unsigned int a3) {
    union { uint4 u; bf16x8 b; } cv;
    cv.u = make_uint4(a0, a1, a2, a3);
    return cv.b;
}
// tanh-approx gelu via exp2 (branch-free)
__device__ __forceinline__ float gelu_tanh(float v) {
    float t = v * fmaf(0.102951871f, v * v, 2.302110084f);
    float s = __builtin_amdgcn_exp2f(t);
    return v - v * __builtin_amdgcn_rcpf(1.0f + s);
}

// packed-weight half offsets in d_ws
#define OQ  0
#define OKk 16384
#define OV  32768
#define OP  49152
#define O1  65536
#define O2  131072

// ---- FUSED weight pre-pack: all 6 weights in ONE launch (saves 5 graph nodes).
__global__ void pack_all(const float* __restrict__ wq, const float* __restrict__ wk,
                         const float* __restrict__ wv, const float* __restrict__ wp,
                         const float* __restrict__ w1, const float* __restrict__ w2,
                         unsigned short* __restrict__ ws16) {
    int b = blockIdx.x;
    const float* src; unsigned short* dst; int K, N, mode, lb; float scale;
    if (b < 64)       { src = wq; dst = ws16 + OQ;  K = 128; N = 128; mode = 1; scale = 0.3606737602f; lb = b; }
    else if (b < 128) { src = wk; dst = ws16 + OKk; K = 128; N = 128; mode = 1; scale = 1.0f; lb = b - 64; }
    else if (b < 192) { src = wv; dst = ws16 + OV;  K = 128; N = 128; mode = 1; scale = 1.0f; lb = b - 128; }
    else if (b < 256) { src = wp; dst = ws16 + OP;  K = 128; N = 128; mode = 0; scale = 1.0f; lb = b - 192; }
    else if (b < 512) { src = w1; dst = ws16 + O1;  K = 128; N = 512; mode = 0; scale = 1.0f; lb = b - 256; }
    else              { src = w2; dst = ws16 + O2;  K = 512; N = 128; mode = 2; scale = 1.0f; lb = b - 512; }
    int i   = lb * 256 + (int)threadIdx.x;      // sizes are exact multiples of 256
    int j   = i & 7;
    int l   = (i >> 3) & 63;
    int tkt = i >> 9;
    int KT  = K >> 5;
    int nt  = tkt / KT;
    int kt  = tkt - nt * KT;
    int lg  = l >> 4;
    int k;
    if (mode == 2) {
        int kp = (j < 4) ? (lg * 4 + j) : (16 + lg * 4 + (j - 4));
        k = kt * 32 + kp;
    } else {
        k = kt * 32 + lg * 8 + j;
    }
    int n = nt * 16 + (l & 15);
    float v = (mode == 1) ? src[(n >> 4) * (K * 16) + k * 16 + (n & 15)]
                          : src[k * N + n];
    dst[i] = f2bf(v * scale);
}

// One block = 1 batch element (64 rows). 512 threads = 8 waves. ~70 KB LDS -> 2 blocks/CU.
__global__ __launch_bounds__(512, 4) void block_fused(
    const float* __restrict__ x,
    const unsigned short* __restrict__ wpk,
    const float* __restrict__ bp,
    const float* __restrict__ b1, const float* __restrict__ b2,
    const float* __restrict__ g1, const float* __restrict__ be1,
    const float* __restrict__ g2, const float* __restrict__ be2,
    float* __restrict__ out)
{
    __shared__ __align__(16) unsigned short A [9216];  // h -> h2 (stays live through FF)
    __shared__ __align__(16) unsigned short Bq[8704];  // q -> attn concat -> FF exch (rt 0,1)
    __shared__ __align__(16) unsigned short Ck[8704];  // k -> x2
    __shared__ __align__(16) unsigned short Vv[9216];  // vT(permuted) -> FF exch (rt 2,3)

    const int tid  = threadIdx.x;
    const int lane = tid & 63;
    const int wave = tid >> 6;
    const int l15  = lane & 15;
    const int lg   = lane >> 4;
    const int rt   = wave >> 1;         // GEMM-phase row tile (proj/FF)
    const int cg   = wave & 1;          // GEMM-phase column group / FF k-half
    const int row0 = rt * 16 + lg * 4;
    const int hcol = wave * 16;         // this wave's head columns

    const float* xb = x   + (size_t)blockIdx.x * (64 * CC);
    float*       ob = out + (size_t)blockIdx.x * (64 * CC);

    // early-issue QKV weight loads (no deps): latency hides under LN1 (r21 pattern).
    bf16x8 wq4[4], wk4[4], wv4[4];
    {
        const unsigned short* wqb = wpk + OQ  + wave * 2048;
        const unsigned short* wkb = wpk + OKk + wave * 2048;
        const unsigned short* wvb = wpk + OV  + wave * 2048;
        #pragma unroll
        for (int kt = 0; kt < 4; ++kt) {
            wq4[kt] = *(const bf16x8*)&wqb[(kt * 64 + lane) * 8];
            wk4[kt] = *(const bf16x8*)&wkb[(kt * 64 + lane) * 8];
            wv4[kt] = *(const bf16x8*)&wvb[(kt * 64 + lane) * 8];
        }
    }

    // ---------------- LN1: x -> A (h, bf16); WIDE-LANE one-pass ----------------
    // 16-lane row groups: lane owns 8 cols, 4 rows/iter, 4-step butterfly.
    {
        float gg[8], bb[8];
        #pragma unroll
        for (int j = 0; j < 8; ++j) {
            gg[j] = g1[l15 * 8 + j];
            bb[j] = be1[l15 * 8 + j];
        }
        const int grp = lane >> 4;
        #pragma unroll
        for (int it = 0; it < 2; ++it) {
            int r = wave * 8 + it * 4 + grp;
            float4 xa = *(const float4*)&xb[r * CC + l15 * 8];
            float4 xc = *(const float4*)&xb[r * CC + l15 * 8 + 4];
            float xv[8] = {xa.x, xa.y, xa.z, xa.w, xc.x, xc.y, xc.z, xc.w};
            float s = 0.f, q = 0.f;
            #pragma unroll
            for (int j = 0; j < 8; ++j) { s += xv[j]; q = fmaf(xv[j], xv[j], q); }
            #pragma unroll
            for (int off = 1; off < 16; off <<= 1) {
                s += __shfl_xor(s, off);
                q += __shfl_xor(q, off);
            }
            float mean = s * (1.0f / CC);
            float var  = fmaf(-mean, mean, q * (1.0f / CC));
            float rstd = __builtin_amdgcn_rsqf(var + 1e-5f);
            unsigned int u0 = f2bf2u(fmaf(gg[0], (xv[0] - mean) * rstd, bb[0]),
                                     fmaf(gg[1], (xv[1] - mean) * rstd, bb[1]));
            unsigned int u1 = f2bf2u(fmaf(gg[2], (xv[2] - mean) * rstd, bb[2]),
                                     fmaf(gg[3], (xv[3] - mean) * rstd, bb[3]));
            unsigned int u2 = f2bf2u(fmaf(gg[4], (xv[4] - mean) * rstd, bb[4]),
                                     fmaf(gg[5], (xv[5] - mean) * rstd, bb[5]));
            unsigned int u3 = f2bf2u(fmaf(gg[6], (xv[6] - mean) * rstd, bb[6]),
                                     fmaf(gg[7], (xv[7] - mean) * rstd, bb[7]));
            *(uint4*)&A[r * RLD + l15 * 8] = make_uint4(u0, u1, u2, u3);
        }
    }
    __syncthreads();

    // ---------------- QKV, head-major: wave = head; weights preloaded ----
    {
        #pragma unroll
        for (int rt2 = 0; rt2 < 4; ++rt2) {
            bf16x8 la[4];
            #pragma unroll
            for (int kt = 0; kt < 4; ++kt)
                la[kt] = *(const bf16x8*)&A[(rt2 * 16 + l15) * RLD + kt * 32 + lg * 8];
            f32x4 cq = {0.f,0.f,0.f,0.f}, ck = {0.f,0.f,0.f,0.f}, cv = {0.f,0.f,0.f,0.f};
            __builtin_amdgcn_s_setprio(1);
            #pragma unroll
            for (int kt = 0; kt < 4; ++kt) {
                cq = MFMA16(la[kt], wq4[kt], cq);
                ck = MFMA16(la[kt], wk4[kt], ck);
                cv = MFMA16(la[kt], wv4[kt], cv);
            }
            __builtin_amdgcn_s_setprio(0);
            int rw = rt2 * 16 + lg * 4;
            unsigned int q01 = f2bf2u(cq[0], cq[1]), q23 = f2bf2u(cq[2], cq[3]);
            unsigned int k01 = f2bf2u(ck[0], ck[1]), k23 = f2bf2u(ck[2], ck[3]);
            unsigned int v01 = f2bf2u(cv[0], cv[1]), v23 = f2bf2u(cv[2], cv[3]);
            int o = rw * RLD + hcol + l15;
            Bq[o]           = (unsigned short)q01;
            Bq[o + RLD]     = (unsigned short)(q01 >> 16);
            Bq[o + 2 * RLD] = (unsigned short)q23;
            Bq[o + 3 * RLD] = (unsigned short)(q23 >> 16);
            Ck[o]           = (unsigned short)k01;
            Ck[o + RLD]     = (unsigned short)(k01 >> 16);
            Ck[o + 2 * RLD] = (unsigned short)k23;
            Ck[o + 3 * RLD] = (unsigned short)(k23 >> 16);
            int vslot = (rt2 >> 1) * 32 + lg * 8 + (rt2 & 1) * 4;
            *(uint2*)&Vv[(hcol + l15) * VLD + vslot] = make_uint2(v01, v23);
        }
    }

    // prefetch proj's residual x (hides under attention); static indices
    float xpre[16];
    #pragma unroll
    for (int ntl = 0; ntl < 4; ++ntl) {
        int col = (cg * 4 + ntl) * 16 + l15;
        #pragma unroll
        for (int r = 0; r < 4; ++r)
            xpre[ntl * 4 + r] = xb[(row0 + r) * CC + col];
    }
    // NO barrier: attention reads only this wave's own q/k/vT

    // ---------------- attention: wave = head, swapped scores, in-register P ----------------
    bf16x8 pp[4];
    {
        int nt0 = cg * 4;
        #pragma unroll
        for (int kt = 0; kt < 4; ++kt)
            pp[kt] = *(const bf16x8*)&wpk[OP + ((nt0 * 4 + kt) * 64 + lane) * 8];
    }
    {
        bf16x8 zf = {0, 0, 0, 0, 0, 0, 0, 0};
        bf16x8 kf[4];
        #pragma unroll
        for (int st = 0; st < 4; ++st)
            kf[st] = (lane < 32) ? *(const bf16x8*)&Ck[(st * 16 + l15) * RLD + hcol + lg * 8] : zf;
        bf16x8 bvf[2];
        #pragma unroll
        for (int kt = 0; kt < 2; ++kt)
            bvf[kt] = *(const bf16x8*)&Vv[(hcol + l15) * VLD + kt * 32 + lg * 8];

        f32x4 ocs[4];
        #pragma unroll
        for (int mt = 0; mt < 4; ++mt) {
            bf16x8 qf = zf;
            if (lane < 32)
                qf = *(const bf16x8*)&Bq[(mt * 16 + l15) * RLD + hcol + lg * 8];
            f32x4 sfr[4];
            __builtin_amdgcn_s_setprio(1);
            #pragma unroll
            for (int st = 0; st < 4; ++st) {
                sfr[st] = (f32x4){0.f, 0.f, 0.f, 0.f};
                if (st <= mt) sfr[st] = MFMA16(kf[st], qf, sfr[st]);
            }
            __builtin_amdgcn_s_setprio(0);
            float e[4][4];
            float sum = 0.f;
            #pragma unroll
            for (int st = 0; st < 4; ++st) {
                #pragma unroll
                for (int r = 0; r < 4; ++r) {
                    float ev = 0.f;
                    if (st < mt) ev = __builtin_amdgcn_exp2f(sfr[st][r]);
                    else if (st == mt)
                        ev = (lg * 4 + r <= l15) ? __builtin_amdgcn_exp2f(sfr[st][r]) : 0.f;
                    e[st][r] = ev;
                    sum += ev;
                }
            }
            sum += __shfl_xor(sum, 16);
            sum += __shfl_xor(sum, 32);
            float inv = __builtin_amdgcn_rcpf(sum);
            unsigned int u[4][2];
            #pragma unroll
            for (int st = 0; st < 4; ++st) {
                if (st <= mt) {
                    u[st][0] = f2bf2u(e[st][0] * inv, e[st][1] * inv);
                    u[st][1] = f2bf2u(e[st][2] * inv, e[st][3] * inv);
                } else { u[st][0] = 0u; u[st][1] = 0u; }
            }
            f32x4 oc = {0.f, 0.f, 0.f, 0.f};
            __builtin_amdgcn_s_setprio(1);
            #pragma unroll
            for (int kt = 0; kt < 2; ++kt) {
                if (kt <= (mt >> 1)) {
                    bf16x8 pa = mk_bf16x8(u[2 * kt][0], u[2 * kt][1],
                                          u[2 * kt + 1][0], u[2 * kt + 1][1]);
                    oc = MFMA16(pa, bvf[kt], oc);
                }
            }
            __builtin_amdgcn_s_setprio(0);
            ocs[mt] = oc;
        }
        #pragma unroll
        for (int mt = 0; mt < 4; ++mt) {
            unsigned int u01 = f2bf2u(ocs[mt][0], ocs[mt][1]);
            unsigned int u23 = f2bf2u(ocs[mt][2], ocs[mt][3]);
            int o = (mt * 16 + lg * 4) * RLD + hcol + l15;
            Bq[o]           = (unsigned short)u01;
            Bq[o + RLD]     = (unsigned short)(u01 >> 16);
            Bq[o + 2 * RLD] = (unsigned short)u23;
            Bq[o + 3 * RLD] = (unsigned short)(u23 >> 16);
        }
    }
    __syncthreads();   // proj reads all columns of Bq

    // ---------------- proj + residual: x2 = x + attn @ Wp + bp -> Ck ----------------
    // ntl=0 peeled onto the prefetched pp[] weights
    {
        bf16x8 pa[4];
        #pragma unroll
        for (int kt = 0; kt < 4; ++kt)
            pa[kt] = *(const bf16x8*)&Bq[(rt * 16 + l15) * RLD + kt * 32 + lg * 8];
        {
            int nt = cg * 4;
            f32x4 c = {0.f, 0.f, 0.f, 0.f};
            #pragma unroll
            for (int kt = 0; kt < 4; ++kt)
                c = MFMA16(pa[kt], pp[kt], c);
            int col = nt * 16 + l15;
            float bpv = bp[col];
            unsigned int u01 = f2bf2u(xpre[0] + c[0] + bpv, xpre[1] + c[1] + bpv);
            unsigned int u23 = f2bf2u(xpre[2] + c[2] + bpv, xpre[3] + c[3] + bpv);
            int o = row0 * RLD + col;
            Ck[o]           = (unsigned short)u01;
            Ck[o + RLD]     = (unsigned short)(u01 >> 16);
            Ck[o + 2 * RLD] = (unsigned short)u23;
            Ck[o + 3 * RLD] = (unsigned short)(u23 >> 16);
        }
        #pragma unroll
        for (int ntl = 1; ntl < 4; ++ntl) {
            int nt = cg * 4 + ntl;
            f32x4 c = {0.f, 0.f, 0.f, 0.f};
            #pragma unroll
            for (int kt = 0; kt < 4; ++kt) {
                bf16x8 b = *(const bf16x8*)&wpk[OP + ((nt * 4 + kt) * 64 + lane) * 8];
                c = MFMA16(pa[kt], b, c);
            }
            int col = nt * 16 + l15;
            float bpv = bp[col];
            unsigned int u01 = f2bf2u(xpre[ntl * 4 + 0] + c[0] + bpv,
                                      xpre[ntl * 4 + 1] + c[1] + bpv);
            unsigned int u23 = f2bf2u(xpre[ntl * 4 + 2] + c[2] + bpv,
                                      xpre[ntl * 4 + 3] + c[3] + bpv);
            int o = row0 * RLD + col;
            Ck[o]           = (unsigned short)u01;
            Ck[o + RLD]     = (unsigned short)(u01 >> 16);
            Ck[o + 2 * RLD] = (unsigned short)u23;
            Ck[o + 3 * RLD] = (unsigned short)(u23 >> 16);
        }
    }
    __syncthreads();   // LN2 reads all cols of Ck; also: last Bq reads complete

    // early-issue FF c=0 weight loads (no LDS dependency): latency hides under LN2.
    bf16x8 pw0[4], pw1[4], pb2[8];
    {
        int t0 = cg * 16;
        #pragma unroll
        for (int kt = 0; kt < 4; ++kt) {
            pw0[kt] = *(const bf16x8*)&wpk[O1 + ((t0 * 4 + kt) * 64 + lane) * 8];
            pw1[kt] = *(const bf16x8*)&wpk[O1 + (((t0 + 1) * 4 + kt) * 64 + lane) * 8];
        }
        int kc = cg * 8;
        #pragma unroll
        for (int nt = 0; nt < 8; ++nt)
            pb2[nt] = *(const bf16x8*)&wpk[O2 + ((nt * 16 + kc) * 64 + lane) * 8];
    }

    // ---------------- LN2: Ck(x2) -> A(h2); WIDE-LANE one-pass ----------------
    {
        float gg[8], bb[8];
        #pragma unroll
        for (int j = 0; j < 8; ++j) {
            gg[j] = g2[l15 * 8 + j];
            bb[j] = be2[l15 * 8 + j];
        }
        const int grp = lane >> 4;
        #pragma unroll
        for (int it = 0; it < 2; ++it) {
            int r = wave * 8 + it * 4 + grp;
            bf16x8 cv = *(const bf16x8*)&Ck[r * RLD + l15 * 8];
            float xv[8];
            #pragma unroll
            for (int j = 0; j < 8; ++j) xv[j] = bf2f((unsigned short)cv[j]);
            float s = 0.f, q = 0.f;
            #pragma unroll
            for (int j = 0; j < 8; ++j) { s += xv[j]; q = fmaf(xv[j], xv[j], q); }
            #pragma unroll
            for (int off = 1; off < 16; off <<= 1) {
                s += __shfl_xor(s, off);
                q += __shfl_xor(q, off);
            }
            float mean = s * (1.0f / CC);
            float var  = fmaf(-mean, mean, q * (1.0f / CC));
            float rstd = __builtin_amdgcn_rsqf(var + 1e-5f);
            unsigned int u0 = f2bf2u(fmaf(gg[0], (xv[0] - mean) * rstd, bb[0]),
                                     fmaf(gg[1], (xv[1] - mean) * rstd, bb[1]));
            unsigned int u1 = f2bf2u(fmaf(gg[2], (xv[2] - mean) * rstd, bb[2]),
                                     fmaf(gg[3], (xv[3] - mean) * rstd, bb[3]));
            unsigned int u2 = f2bf2u(fmaf(gg[4], (xv[4] - mean) * rstd, bb[4]),
                                     fmaf(gg[5], (xv[5] - mean) * rstd, bb[5]));
            unsigned int u3 = f2bf2u(fmaf(gg[6], (xv[6] - mean) * rstd, bb[6]),
                                     fmaf(gg[7], (xv[7] - mean) * rstd, bb[7]));
            *(uint4*)&A[r * RLD + l15 * 8] = make_uint4(u0, u1, u2, u3);
        }
    }
    __syncthreads();

    // ---------------- FF, wave-private K-split (no LDS f1, no inner barriers) -------
    {
        bf16x8 ha[4];
        #pragma unroll
        for (int kt = 0; kt < 4; ++kt)
            ha[kt] = *(const bf16x8*)&A[(rt * 16 + l15) * RLD + kt * 32 + lg * 8];
        f32x4 facc[8];
        #pragma unroll
        for (int n = 0; n < 8; ++n) facc[n] = (f32x4){0.f, 0.f, 0.f, 0.f};

        // peeled c=0 using the prefetched FF1 + FF2 weights
        {
            int t0 = cg * 16;
            f32x4 c0 = {0.f,0.f,0.f,0.f}, c1 = {0.f,0.f,0.f,0.f};
            #pragma unroll
            for (int kt = 0; kt < 4; ++kt) {
                c0 = MFMA16(pw0[kt], ha[kt], c0);   // transposed: C[col=token][row=f]
                c1 = MFMA16(pw1[kt], ha[kt], c1);
            }
            int fb = t0 * 16 + lg * 4;
            float g0[4], g1v[4];
            #pragma unroll
            for (int r = 0; r < 4; ++r) g0[r]  = gelu_tanh(c0[r] + b1[fb + r]);
            #pragma unroll
            for (int r = 0; r < 4; ++r) g1v[r] = gelu_tanh(c1[r] + b1[fb + 16 + r]);
            bf16x8 pa = mk_bf16x8(f2bf2u(g0[0],  g0[1]),  f2bf2u(g0[2],  g0[3]),
                                  f2bf2u(g1v[0], g1v[1]), f2bf2u(g1v[2], g1v[3]));
            #pragma unroll
            for (int nt = 0; nt < 8; ++nt)
                facc[nt] = MFMA16(pa, pb2[nt], facc[nt]);
        }

        #pragma unroll 1
        for (int c = 1; c < 8; ++c) {            // K32 chunk = 2 f-tiles
            int t0 = cg * 16 + 2 * c;
            f32x4 c0 = {0.f,0.f,0.f,0.f}, c1 = {0.f,0.f,0.f,0.f};
            #pragma unroll
            for (int kt = 0; kt < 4; ++kt) {
                bf16x8 w0  = *(const bf16x8*)&wpk[O1 + ((t0 * 4 + kt) * 64 + lane) * 8];
                bf16x8 w1f = *(const bf16x8*)&wpk[O1 + (((t0 + 1) * 4 + kt) * 64 + lane) * 8];
                c0 = MFMA16(w0,  ha[kt], c0);    // transposed: C[col=token][row=f]
                c1 = MFMA16(w1f, ha[kt], c1);
            }
            int fb = t0 * 16 + lg * 4;
            float g0[4], g1v[4];
            #pragma unroll
            for (int r = 0; r < 4; ++r) g0[r]  = gelu_tanh(c0[r] + b1[fb + r]);
            #pragma unroll
            for (int r = 0; r < 4; ++r) g1v[r] = gelu_tanh(c1[r] + b1[fb + 16 + r]);
            bf16x8 pa = mk_bf16x8(f2bf2u(g0[0],  g0[1]),  f2bf2u(g0[2],  g0[3]),
                                  f2bf2u(g1v[0], g1v[1]), f2bf2u(g1v[2], g1v[3]));
            int kc = cg * 8 + c;
            #pragma unroll
            for (int nt = 0; nt < 8; ++nt) {
                bf16x8 b = *(const bf16x8*)&wpk[O2 + ((nt * 16 + kc) * 64 + lane) * 8];
                facc[nt] = MFMA16(pa, b, facc[nt]);
            }
        }

        // NO barrier here: exchange targets Bq (dead since proj) and Vv (dead
        // since attention) — A(h2) is never overwritten (r27 layout).
        float* fb0 = (rt < 2) ? (float*)Bq : (float*)Vv;
        const int fbase = (rt & 1) * 2112;        // [16 tokens][132 f32] per tile
        if (cg == 0) {
            #pragma unroll
            for (int n2 = 0; n2 < 4; ++n2)
                #pragma unroll
                for (int r = 0; r < 4; ++r)
                    fb0[fbase + (lg * 4 + r) * 132 + (n2 + 4) * 16 + l15] = facc[n2 + 4][r];
        } else {
            #pragma unroll
            for (int n2 = 0; n2 < 4; ++n2)
                #pragma unroll
                for (int r = 0; r < 4; ++r)
                    fb0[fbase + (lg * 4 + r) * 132 + n2 * 16 + l15] = facc[n2][r];
        }
        __syncthreads();   // partner's partials visible
        if (cg == 0) {
            #pragma unroll
            for (int n2 = 0; n2 < 4; ++n2) {
                int col = n2 * 16 + l15;
                float b2v = b2[col];
                #pragma unroll
                for (int r = 0; r < 4; ++r) {
                    int row = row0 + r;
                    ob[row * CC + col] = bf2f(Ck[row * RLD + col]) + facc[n2][r]
                                       + fb0[fbase + (lg * 4 + r) * 132 + col] + b2v;
                }
            }
        } else {
            #pragma unroll
            for (int n2 = 0; n2 < 4; ++n2) {
                int col = (n2 + 4) * 16 + l15;
                float b2v = b2[col];
                #pragma unroll
                for (int r = 0; r < 4; ++r) {
                    int row = row0 + r;
                    ob[row * CC + col] = bf2f(Ck[row * RLD + col]) + facc[n2 + 4][r]
                                       + fb0[fbase + (lg * 4 + r) * 132 + col] + b2v;
                }
            }
        }
    }
}

extern "C" void kernel_launch(void* const* d_in, const int* in_sizes, int n_in,
                              void* d_out, int out_size, void* d_ws, size_t ws_size,
                              hipStream_t stream) {
    (void)n_in; (void)out_size; (void)ws_size;
    const float* x   = (const float*)d_in[0];
    const float* wq  = (const float*)d_in[1];
    const float* wk  = (const float*)d_in[2];
    const float* wv  = (const float*)d_in[3];
    const float* wp  = (const float*)d_in[4];
    const float* bp  = (const float*)d_in[5];
    const float* w1  = (const float*)d_in[6];
    const float* b1  = (const float*)d_in[7];
    const float* w2  = (const float*)d_in[8];
    const float* b2  = (const float*)d_in[9];
    const float* g1  = (const float*)d_in[10];
    const float* be1 = (const float*)d_in[11];
    const float* g2  = (const float*)d_in[12];
    const float* be2 = (const float*)d_in[13];

    unsigned short* ws16 = (unsigned short*)d_ws;
    // all 6 weight packs in ONE launch (saves 5 graph-node overheads);
    // wq scale = HD^-0.5 * log2(e) folded inside (base-2 softmax domain)
    pack_all<<<768, 256, 0, stream>>>(wq, wk, wv, wp, w1, w2, ws16);

    int nblk = in_sizes[0] / (64 * CC);   // one block per batch element
    block_fused<<<dim3(nblk), dim3(512), 0, stream>>>(
        x, ws16, bp, b1, b2, g1, be1, g2, be2, (float*)d_out);
}